// Round 16
// baseline (263.288 us; speedup 1.0000x reference)
//
#include <hip/hip_runtime.h>

// LowRankRotatedSpaceIntervention — v16: K1 rebuilt in K2's image.
// out[b,:] = base[b,:] + (mask_b . ((source[b,:]-base[b,:]) @ W)) @ W^T
// B=16384, D=4096, R=64, 8 partitions of 8, 4 selected per row.
//
// R15 split localized the bottleneck: K1 (LDS-staged, vmcnt-ledger) = 165us
// @3.1 TB/s delivered; K2 (plain register loads, compiler waits, 16 w/CU)
// = ~65us @~6 TB/s delivered. The plateau was my phase-1 staging structure.
// v16-K1: swapped MFMA operands (A=W^T frag from ws [contiguous 16B, L2-hot],
// B=diff frag = 8 consecutive fp32 of ONE batch row = 2 contiguous float4
// register loads). No LDS in the loop, no asm, no global_load_lds; explicit
// source-level register double-buffer (named sets, static indexing) forces
// one chunk of loads in flight during compute. LDS only for the cross-wave
// reduce (17KB). K2 + prep byte-identical to v15.

#define D_DIM 4096
#define R_DIM 64
#define BM1   16               // K1 rows/block -> 1024 blocks
#define BM2   32               // K2 rows/block -> 512 blocks

typedef short bf16vec8 __attribute__((ext_vector_type(8)));
typedef float f32x4v  __attribute__((ext_vector_type(4)));

__device__ __forceinline__ unsigned int f2bf_u(float f) {
  unsigned int u = __builtin_bit_cast(unsigned int, f);
  return (u + 0x7fffu + ((u >> 16) & 1u)) >> 16;   // RNE
}
__device__ __forceinline__ unsigned int pack2bf(float a, float b) {
  return f2bf_u(a) | (f2bf_u(b) << 16);
}
__device__ __forceinline__ void async_ld16(const void* g, void* l) {
  __builtin_amdgcn_global_load_lds(
      (const __attribute__((address_space(1))) void*)g,
      (__attribute__((address_space(3))) void*)l, 16, 0, 0);
}

__global__ __launch_bounds__(256)
void lrri_prep(const float* __restrict__ W, unsigned short* __restrict__ Wt,
               unsigned short* __restrict__ Wb) {
  const int idx = blockIdx.x * blockDim.x + threadIdx.x;   // 0..65535
  const int k = idx >> 4;
  const int j = (idx & 15) * 4;
  float4 w = *(const float4*)(W + (size_t)k * R_DIM + j);
  ushort4 p;
  p.x = (unsigned short)f2bf_u(w.x);
  p.y = (unsigned short)f2bf_u(w.y);
  p.z = (unsigned short)f2bf_u(w.z);
  p.w = (unsigned short)f2bf_u(w.w);
  *(ushort4*)(Wb + (size_t)k * R_DIM + j) = p;     // [4096][64] bf16
  Wt[(size_t)(j + 0) * D_DIM + k] = p.x;           // [64][4096] bf16
  Wt[(size_t)(j + 1) * D_DIM + k] = p.y;
  Wt[(size_t)(j + 2) * D_DIM + k] = p.z;
  Wt[(size_t)(j + 3) * D_DIM + k] = p.w;
}

// ========== K1: rm = mask . ((src-base) @ W), register-streamed ==========
// Swapped operands: C[j][row] = sum_k Wt[j][k] * diff[row][k].
// A-frag (W): lane(l4,g) holds A[m=l4][k=s*32+g*8+e] -> Wt_bf row t*16+l4,
//   16B contiguous. B-frag (diff): lane(l4,g) holds B[k][n=l4] -> 8
//   consecutive fp32 of batch row l4. C: lane(l4,g) reg i = C[j=g*4+i][l4].
__global__ __launch_bounds__(256, 3)
void k1_rotdiff(const float* __restrict__ base, const float* __restrict__ srcp,
                const int* __restrict__ subs,
                const unsigned short* __restrict__ Wt_bf,   // [64][4096]
                unsigned short* __restrict__ rm_g)          // [16384][64]
{
  __shared__ __align__(16) float part[4][64 * 17];   // 17408 B
  const int tid  = threadIdx.x;
  const int wave = tid >> 6;
  const int lane = tid & 63;
  const int l4   = lane & 15;
  const int g    = lane >> 4;
  const long rowbase = (long)blockIdx.x * BM1;
  const long rowA    = (rowbase + l4) * (long)D_DIM;   // this lane's row
  const int  kq0     = wave * 1024;                    // wave's K-quarter
  const int  off1    = (blockIdx.x * 5) & 15;          // chunk stagger

  f32x4v acc[4];
  #pragma unroll
  for (int t = 0; t < 4; ++t) acc[t] = (f32x4v){0.f, 0.f, 0.f, 0.f};

  // load chunk c (64 cols) of this lane's row: 4+4 contiguous float4
  auto loadd = [&](int c, float4 (&vb)[4], float4 (&vs)[4]) {
    const int ch = (c + off1) & 15;
    const long colf = kq0 + ch * 64;
    #pragma unroll
    for (int q = 0; q < 4; ++q) {          // q = s*2 + half
      const long off = rowA + colf + (q >> 1) * 32 + g * 8 + (q & 1) * 4;
      vb[q] = *(const float4*)(base + off);
      vs[q] = *(const float4*)(srcp + off);
    }
  };

  auto comp = [&](int c, const float4 (&vb)[4], const float4 (&vs)[4]) {
    const int ch = (c + off1) & 15;
    const long colf = kq0 + ch * 64;
    uint4 df[2];
    #pragma unroll
    for (int s = 0; s < 2; ++s) {
      float d0 = vs[s*2].x - vb[s*2].x, d1 = vs[s*2].y - vb[s*2].y;
      float d2 = vs[s*2].z - vb[s*2].z, d3 = vs[s*2].w - vb[s*2].w;
      float d4 = vs[s*2+1].x - vb[s*2+1].x, d5 = vs[s*2+1].y - vb[s*2+1].y;
      float d6 = vs[s*2+1].z - vb[s*2+1].z, d7 = vs[s*2+1].w - vb[s*2+1].w;
      df[s].x = pack2bf(d0, d1);
      df[s].y = pack2bf(d2, d3);
      df[s].z = pack2bf(d4, d5);
      df[s].w = pack2bf(d6, d7);
    }
    #pragma unroll
    for (int t = 0; t < 4; ++t) {
      #pragma unroll
      for (int s = 0; s < 2; ++s) {
        uint4 wf = *(const uint4*)(Wt_bf + (size_t)(t * 16 + l4) * D_DIM +
                                   colf + s * 32 + g * 8);   // L2-hot
        acc[t] = __builtin_amdgcn_mfma_f32_16x16x32_bf16(
            __builtin_bit_cast(bf16vec8, wf),      // A = W^T fragment
            __builtin_bit_cast(bf16vec8, df[s]),   // B = diff fragment
            acc[t], 0, 0, 0);
      }
    }
  };

  // explicit register double-buffer: loads of c+1 issued before compute(c)
  float4 b0[4], s0[4], b1[4], s1[4];
  loadd(0, b0, s0);
  #pragma unroll 1
  for (int cc = 0; cc < 14; cc += 2) {
    loadd(cc + 1, b1, s1);
    comp(cc, b0, s0);
    loadd(cc + 2, b0, s0);
    comp(cc + 1, b1, s1);
  }
  loadd(15, b1, s1);
  comp(14, b0, s0);
  comp(15, b1, s1);

  // partials: C[j = t*16 + g*4 + i][row = l4]
  #pragma unroll
  for (int t = 0; t < 4; ++t)
    #pragma unroll
    for (int i = 0; i < 4; ++i)
      part[wave][(t * 16 + g * 4 + i) * 17 + l4] = acc[t][i];
  __syncthreads();

  // reduce 4 K-quarters + per-row partition mask -> global rm
  {
    const int row = tid >> 4, jg = tid & 15;
    int4 sb = *(const int4*)(subs + (rowbase + row) * 4);
    unsigned mbits = (1u << sb.x) | (1u << sb.y) | (1u << sb.z) | (1u << sb.w);
    unsigned short v[4];
    #pragma unroll
    for (int jj = 0; jj < 4; ++jj) {
      const int j = jg * 4 + jj;
      float sum = part[0][j * 17 + row] + part[1][j * 17 + row] +
                  part[2][j * 17 + row] + part[3][j * 17 + row];
      v[jj] = ((mbits >> (j >> 3)) & 1u) ? (unsigned short)f2bf_u(sum)
                                         : (unsigned short)0;
    }
    uint2 pk;
    pk.x = (unsigned)v[0] | ((unsigned)v[1] << 16);
    pk.y = (unsigned)v[2] | ((unsigned)v[3] << 16);
    *(uint2*)(rm_g + (rowbase + row) * 64 + jg * 4) = pk;
  }
}

// ===================== K2: out = base + rm @ W^T  [v15 verbatim] ==========
__global__ __launch_bounds__(256, 4)
void k2_apply(const float* __restrict__ base,
              const unsigned short* __restrict__ rm_g,     // [16384][64]
              const unsigned short* __restrict__ Wb_bf,    // [4096][64]
              float* __restrict__ out)
{
  __shared__ __align__(16) unsigned char smem[36864];   // 4 x [32][72] f32
  const int tid  = threadIdx.x;
  const int wave = tid >> 6;
  const int lane = tid & 63;
  const int l4   = lane & 15;
  const int g    = lane >> 4;
  const long rowbase = (long)blockIdx.x * BM2;
  const int off2 = (blockIdx.x * 5) & 15;

  uint4 a2[2][2];     // [row-tile m][k-split s] from global rm (L2-hot, 2MB)
  #pragma unroll
  for (int m = 0; m < 2; ++m)
    #pragma unroll
    for (int s = 0; s < 2; ++s)
      a2[m][s] = *(const uint4*)(rm_g + (rowbase + m * 16 + l4) * 64 +
                                 s * 32 + g * 8);

  float* cbuf = (float*)(smem + wave * 9216);   // [32][72] f32, wave-private
  #pragma unroll 1
  for (int grp = 0; grp < 16; ++grp) {
    const int ga = (grp + off2) & 15;
    const int cbase = wave * 1024 + ga * 64;
    float4 bb[8];
    #pragma unroll
    for (int v2 = 0; v2 < 8; ++v2) {
      const int r = g + v2 * 4;
      bb[v2] = *(const float4*)(base + (rowbase + r) * D_DIM + cbase + l4 * 4);
    }
    f32x4v a[2][4];
    #pragma unroll
    for (int m = 0; m < 2; ++m)
      #pragma unroll
      for (int t = 0; t < 4; ++t) a[m][t] = (f32x4v){0.f, 0.f, 0.f, 0.f};
    #pragma unroll
    for (int t = 0; t < 4; ++t) {
      #pragma unroll
      for (int s = 0; s < 2; ++s) {
        uint4 bfrag = *(const uint4*)(Wb_bf +
            (size_t)(cbase + t * 16 + l4) * R_DIM + s * 32 + g * 8);
        #pragma unroll
        for (int m = 0; m < 2; ++m)
          a[m][t] = __builtin_amdgcn_mfma_f32_16x16x32_bf16(
              __builtin_bit_cast(bf16vec8, a2[m][s]),
              __builtin_bit_cast(bf16vec8, bfrag), a[m][t], 0, 0, 0);
      }
    }
    #pragma unroll
    for (int m = 0; m < 2; ++m)
      #pragma unroll
      for (int t = 0; t < 4; ++t)
        #pragma unroll
        for (int i = 0; i < 4; ++i)
          cbuf[(m * 16 + g * 4 + i) * 72 + t * 16 + l4] = a[m][t][i];
    __syncthreads();
    #pragma unroll
    for (int v2 = 0; v2 < 8; ++v2) {
      const int r = g + v2 * 4;
      f32x4v cv = *(const f32x4v*)(cbuf + r * 72 + l4 * 4);
      float4 o;
      o.x = cv[0] + bb[v2].x;
      o.y = cv[1] + bb[v2].y;
      o.z = cv[2] + bb[v2].z;
      o.w = cv[3] + bb[v2].w;
      *(float4*)(out + (rowbase + r) * D_DIM + cbase + l4 * 4) = o;
    }
    __syncthreads();
  }
}

// ===================== fused fallback (no ws) [v15 verbatim] ==============
__global__ __launch_bounds__(256, 2)
void lrri_fused_nows(const float* __restrict__ base, const float* __restrict__ srcp,
                     const float* __restrict__ W, const int* __restrict__ subs,
                     float* __restrict__ out)
{
  __shared__ __align__(16) unsigned char smem[70144];
  const int tid  = threadIdx.x;
  const int wave = tid >> 6;
  const int lane = tid & 63;
  const int l4   = lane & 15;
  const int g    = lane >> 4;
  const int rh   = wave >> 1;
  const int kh   = wave & 1;
  const long rowbase = (long)blockIdx.x * BM2;
  const long rowg    = rowbase + rh * 16;
  unsigned char* wbuf = smem + wave * 16384;
  const int off1 = (blockIdx.x * 7) & 63;
  const int off2 = (blockIdx.x * 5) & 15;

  f32x4v acc[4];
  #pragma unroll
  for (int t = 0; t < 4; ++t) acc[t] = (f32x4v){0.f, 0.f, 0.f, 0.f};

  #pragma unroll 1
  for (int c = 0; c < 64; ++c) {
    const int ch = (c + off1) & 63;
    unsigned char* buf = wbuf + (c & 1) * 8192;
    const long colf = kh * 2048 + ch * 32;
    #pragma unroll
    for (int q = 0; q < 2; ++q) {
      const int r = q * 8 + (lane >> 3);
      const unsigned b = ((unsigned)((lane & 7) * 16)) ^ ((unsigned)(r & 7) << 4);
      const long goff = (rowg + r) * (long)D_DIM + colf + (b >> 2);
      async_ld16(base + goff, buf + q * 1024);
      async_ld16(srcp + goff, buf + 2048 + q * 1024);
    }
    asm volatile("s_waitcnt vmcnt(0)" ::: "memory");
    __builtin_amdgcn_sched_barrier(0);
    const unsigned sw = (unsigned)((l4 & 7) << 4);
    const unsigned c0 = ((unsigned)(g * 32)) ^ sw;
    const unsigned c1 = ((unsigned)(g * 32 + 16)) ^ sw;
    float4 fb0 = *(const float4*)(buf + l4 * 128 + c0);
    float4 fb1 = *(const float4*)(buf + l4 * 128 + c1);
    float4 fs0 = *(const float4*)(buf + 2048 + l4 * 128 + c0);
    float4 fs1 = *(const float4*)(buf + 2048 + l4 * 128 + c1);
    uint4 af;
    af.x = pack2bf(fs0.x - fb0.x, fs0.y - fb0.y);
    af.y = pack2bf(fs0.z - fb0.z, fs0.w - fb0.w);
    af.z = pack2bf(fs1.x - fb1.x, fs1.y - fb1.y);
    af.w = pack2bf(fs1.z - fb1.z, fs1.w - fb1.w);
    #pragma unroll
    for (int t = 0; t < 4; ++t) {
      unsigned int pq[4];
      #pragma unroll
      for (int e2 = 0; e2 < 4; ++e2) {
        float wa = W[(size_t)(colf + g * 8 + e2 * 2    ) * R_DIM + t * 16 + l4];
        float wb = W[(size_t)(colf + g * 8 + e2 * 2 + 1) * R_DIM + t * 16 + l4];
        pq[e2] = pack2bf(wa, wb);
      }
      uint4 wf; wf.x = pq[0]; wf.y = pq[1]; wf.z = pq[2]; wf.w = pq[3];
      acc[t] = __builtin_amdgcn_mfma_f32_16x16x32_bf16(
          __builtin_bit_cast(bf16vec8, af),
          __builtin_bit_cast(bf16vec8, wf), acc[t], 0, 0, 0);
    }
  }

  {
    float* part = (float*)wbuf;
    #pragma unroll
    for (int t = 0; t < 4; ++t)
      #pragma unroll
      for (int i = 0; i < 4; ++i)
        part[(g * 4 + i) * 72 + t * 16 + l4] = acc[t][i];
  }
  __syncthreads();

  {
    const int row = tid >> 3, jg = tid & 7;
    const int lr  = row & 15;
    const float* pa = (const float*)(smem + ((row >> 4) * 2 + 0) * 16384);
    const float* pb = (const float*)(smem + ((row >> 4) * 2 + 1) * 16384);
    int4 sb = *(const int4*)(subs + (rowbase + row) * 4);
    unsigned mbits = (1u << sb.x) | (1u << sb.y) | (1u << sb.z) | (1u << sb.w);
    unsigned short v[8];
    #pragma unroll
    for (int jj = 0; jj < 8; ++jj) {
      const int j = jg * 8 + jj;
      float sum = pa[lr * 72 + j] + pb[lr * 72 + j];
      v[jj] = ((mbits >> (j >> 3)) & 1u) ? (unsigned short)f2bf_u(sum)
                                         : (unsigned short)0;
    }
    uint4 pk;
    pk.x = (unsigned)v[0] | ((unsigned)v[1] << 16);
    pk.y = (unsigned)v[2] | ((unsigned)v[3] << 16);
    pk.z = (unsigned)v[4] | ((unsigned)v[5] << 16);
    pk.w = (unsigned)v[6] | ((unsigned)v[7] << 16);
    *(uint4*)(smem + 65536 + row * 144 + jg * 16) = pk;
  }
  __syncthreads();

  uint4 a2[2][2];
  #pragma unroll
  for (int m = 0; m < 2; ++m)
    #pragma unroll
    for (int s = 0; s < 2; ++s)
      a2[m][s] = *(const uint4*)(smem + 65536 + (m * 16 + l4) * 144 +
                                 s * 64 + g * 16);
  float* cbuf = (float*)wbuf;
  #pragma unroll 1
  for (int grp = 0; grp < 16; ++grp) {
    const int ga = (grp + off2) & 15;
    const int cbase = wave * 1024 + ga * 64;
    float4 bb[8];
    #pragma unroll
    for (int v2 = 0; v2 < 8; ++v2) {
      const int r = g + v2 * 4;
      bb[v2] = *(const float4*)(base + (rowbase + r) * D_DIM + cbase + l4 * 4);
    }
    f32x4v a[2][4];
    #pragma unroll
    for (int m = 0; m < 2; ++m)
      #pragma unroll
      for (int t = 0; t < 4; ++t) a[m][t] = (f32x4v){0.f, 0.f, 0.f, 0.f};
    #pragma unroll
    for (int t = 0; t < 4; ++t) {
      #pragma unroll
      for (int s = 0; s < 2; ++s) {
        const float* wp = W + (size_t)(cbase + t * 16 + l4) * R_DIM + s * 32 + g * 8;
        float4 wa = *(const float4*)(wp);
        float4 wb2 = *(const float4*)(wp + 4);
        uint4 bfrag;
        bfrag.x = pack2bf(wa.x, wa.y); bfrag.y = pack2bf(wa.z, wa.w);
        bfrag.z = pack2bf(wb2.x, wb2.y); bfrag.w = pack2bf(wb2.z, wb2.w);
        #pragma unroll
        for (int m = 0; m < 2; ++m)
          a[m][t] = __builtin_amdgcn_mfma_f32_16x16x32_bf16(
              __builtin_bit_cast(bf16vec8, a2[m][s]),
              __builtin_bit_cast(bf16vec8, bfrag), a[m][t], 0, 0, 0);
      }
    }
    #pragma unroll
    for (int m = 0; m < 2; ++m)
      #pragma unroll
      for (int t = 0; t < 4; ++t)
        #pragma unroll
        for (int i = 0; i < 4; ++i)
          cbuf[(m * 16 + g * 4 + i) * 72 + t * 16 + l4] = a[m][t][i];
    #pragma unroll
    for (int v2 = 0; v2 < 8; ++v2) {
      const int r = g + v2 * 4;
      f32x4v cv = *(const f32x4v*)(cbuf + r * 72 + l4 * 4);
      float4 o;
      o.x = cv[0] + bb[v2].x;
      o.y = cv[1] + bb[v2].y;
      o.z = cv[2] + bb[v2].z;
      o.w = cv[3] + bb[v2].w;
      *(float4*)(out + (rowbase + r) * D_DIM + cbase + l4 * 4) = o;
    }
  }
}

extern "C" void kernel_launch(void* const* d_in, const int* in_sizes, int n_in,
                              void* d_out, int out_size, void* d_ws, size_t ws_size,
                              hipStream_t stream) {
  const float* base = (const float*)d_in[0];
  const float* srcp = (const float*)d_in[1];
  const float* W    = (const float*)d_in[2];
  const int*   subs = (const int*)d_in[3];
  float* out = (float*)d_out;

  const size_t wconv = (size_t)2 * R_DIM * D_DIM * sizeof(unsigned short); // 1 MB
  const size_t rmsz  = (size_t)16384 * R_DIM * sizeof(unsigned short);     // 2 MB
  if (d_ws && ws_size >= wconv + rmsz) {
    unsigned short* Wt = (unsigned short*)d_ws;          // [64][4096] bf16
    unsigned short* Wb = Wt + (size_t)R_DIM * D_DIM;     // [4096][64] bf16
    unsigned short* rm = Wb + (size_t)R_DIM * D_DIM;     // [16384][64] bf16
    lrri_prep<<<256, 256, 0, stream>>>(W, Wt, Wb);
    k1_rotdiff<<<16384 / BM1, 256, 0, stream>>>(base, srcp, subs, Wt, rm);
    k2_apply<<<16384 / BM2, 256, 0, stream>>>(base, rm, Wb, out);
  } else {
    lrri_fused_nows<<<16384 / BM2, 256, 0, stream>>>(base, srcp, W, subs, out);
  }
}

// Round 17
// 255.978 us; speedup vs baseline: 1.0286x; 1.0286x over previous
//
#include <hip/hip_runtime.h>

// LowRankRotatedSpaceIntervention — v17: K1 at 32 waves/CU (occupancy).
// out[b,:] = base[b,:] + (mask_b . ((source[b,:]-base[b,:]) @ W)) @ W^T
// B=16384, D=4096, R=64, 8 partitions of 8, 4 selected per row.
//
// R16: K1 registered-streamed but OccupancyPercent=39.6 — grid arithmetic
// capped it (1024 blocks / 256 CU = 4 blocks x 4 waves = 16 waves/CU max).
// Every slow K1 variant ran 8-16 waves/CU; memcpy runs 32. v17: same K1
// structure, 512 threads (8 waves x 512-col K-eighths), grid still 1024
// -> 4 blocks x 8 waves = 32 waves/CU. LDS 34.8KB/block (fits 4 blocks),
// launch_bounds(512,8) caps VGPR at 64 (v16 used 60). K2/prep unchanged.

#define D_DIM 4096
#define R_DIM 64
#define BM1   16               // K1 rows/block -> 1024 blocks
#define BM2   32               // K2 rows/block -> 512 blocks

typedef short bf16vec8 __attribute__((ext_vector_type(8)));
typedef float f32x4v  __attribute__((ext_vector_type(4)));

__device__ __forceinline__ unsigned int f2bf_u(float f) {
  unsigned int u = __builtin_bit_cast(unsigned int, f);
  return (u + 0x7fffu + ((u >> 16) & 1u)) >> 16;   // RNE
}
__device__ __forceinline__ unsigned int pack2bf(float a, float b) {
  return f2bf_u(a) | (f2bf_u(b) << 16);
}
__device__ __forceinline__ void async_ld16(const void* g, void* l) {
  __builtin_amdgcn_global_load_lds(
      (const __attribute__((address_space(1))) void*)g,
      (__attribute__((address_space(3))) void*)l, 16, 0, 0);
}

__global__ __launch_bounds__(256)
void lrri_prep(const float* __restrict__ W, unsigned short* __restrict__ Wt,
               unsigned short* __restrict__ Wb) {
  const int idx = blockIdx.x * blockDim.x + threadIdx.x;   // 0..65535
  const int k = idx >> 4;
  const int j = (idx & 15) * 4;
  float4 w = *(const float4*)(W + (size_t)k * R_DIM + j);
  ushort4 p;
  p.x = (unsigned short)f2bf_u(w.x);
  p.y = (unsigned short)f2bf_u(w.y);
  p.z = (unsigned short)f2bf_u(w.z);
  p.w = (unsigned short)f2bf_u(w.w);
  *(ushort4*)(Wb + (size_t)k * R_DIM + j) = p;     // [4096][64] bf16
  Wt[(size_t)(j + 0) * D_DIM + k] = p.x;           // [64][4096] bf16
  Wt[(size_t)(j + 1) * D_DIM + k] = p.y;
  Wt[(size_t)(j + 2) * D_DIM + k] = p.z;
  Wt[(size_t)(j + 3) * D_DIM + k] = p.w;
}

// ========== K1: rm = mask . ((src-base) @ W), 32 waves/CU ================
// Swapped operands: C[j][row] = sum_k Wt[j][k] * diff[row][k].
// A-frag (W): lane(l4,g) holds A[m=l4][k=s*32+g*8+e] -> Wt_bf row t*16+l4,
//   16B contiguous, L2-hot. B-frag (diff): 8 consecutive fp32 of batch row
//   l4 = 2 contiguous float4 register loads. C: reg i = C[j=g*4+i][l4].
__global__ __launch_bounds__(512, 8)
void k1_rotdiff(const float* __restrict__ base, const float* __restrict__ srcp,
                const int* __restrict__ subs,
                const unsigned short* __restrict__ Wt_bf,   // [64][4096]
                unsigned short* __restrict__ rm_g)          // [16384][64]
{
  __shared__ __align__(16) float part[8][64 * 17];   // 34816 B
  const int tid  = threadIdx.x;
  const int wave = tid >> 6;                         // 0..7: K-eighth owner
  const int lane = tid & 63;
  const int l4   = lane & 15;
  const int g    = lane >> 4;
  const long rowbase = (long)blockIdx.x * BM1;
  const long rowA    = (rowbase + l4) * (long)D_DIM; // this lane's row
  const int  kq0     = wave * 512;                   // wave's K-eighth
  const int  off1    = (blockIdx.x * 5) & 7;         // chunk stagger

  f32x4v acc[4];
  #pragma unroll
  for (int t = 0; t < 4; ++t) acc[t] = (f32x4v){0.f, 0.f, 0.f, 0.f};

  // load chunk c (64 cols) of this lane's row: 4+4 contiguous float4
  auto loadd = [&](int c, float4 (&vb)[4], float4 (&vs)[4]) {
    const int ch = (c + off1) & 7;
    const long colf = kq0 + ch * 64;
    #pragma unroll
    for (int q = 0; q < 4; ++q) {          // q = s*2 + half
      const long off = rowA + colf + (q >> 1) * 32 + g * 8 + (q & 1) * 4;
      vb[q] = *(const float4*)(base + off);
      vs[q] = *(const float4*)(srcp + off);
    }
  };

  auto comp = [&](int c, const float4 (&vb)[4], const float4 (&vs)[4]) {
    const int ch = (c + off1) & 7;
    const long colf = kq0 + ch * 64;
    uint4 df[2];
    #pragma unroll
    for (int s = 0; s < 2; ++s) {
      float d0 = vs[s*2].x - vb[s*2].x, d1 = vs[s*2].y - vb[s*2].y;
      float d2 = vs[s*2].z - vb[s*2].z, d3 = vs[s*2].w - vb[s*2].w;
      float d4 = vs[s*2+1].x - vb[s*2+1].x, d5 = vs[s*2+1].y - vb[s*2+1].y;
      float d6 = vs[s*2+1].z - vb[s*2+1].z, d7 = vs[s*2+1].w - vb[s*2+1].w;
      df[s].x = pack2bf(d0, d1);
      df[s].y = pack2bf(d2, d3);
      df[s].z = pack2bf(d4, d5);
      df[s].w = pack2bf(d6, d7);
    }
    #pragma unroll
    for (int t = 0; t < 4; ++t) {
      #pragma unroll
      for (int s = 0; s < 2; ++s) {
        uint4 wf = *(const uint4*)(Wt_bf + (size_t)(t * 16 + l4) * D_DIM +
                                   colf + s * 32 + g * 8);   // L2-hot
        acc[t] = __builtin_amdgcn_mfma_f32_16x16x32_bf16(
            __builtin_bit_cast(bf16vec8, wf),      // A = W^T fragment
            __builtin_bit_cast(bf16vec8, df[s]),   // B = diff fragment
            acc[t], 0, 0, 0);
      }
    }
  };

  // explicit register double-buffer over 8 chunks
  float4 b0[4], s0[4], b1[4], s1[4];
  loadd(0, b0, s0);
  loadd(1, b1, s1); comp(0, b0, s0);
  loadd(2, b0, s0); comp(1, b1, s1);
  loadd(3, b1, s1); comp(2, b0, s0);
  loadd(4, b0, s0); comp(3, b1, s1);
  loadd(5, b1, s1); comp(4, b0, s0);
  loadd(6, b0, s0); comp(5, b1, s1);
  loadd(7, b1, s1); comp(6, b0, s0);
  comp(7, b1, s1);

  // partials: C[j = t*16 + g*4 + i][row = l4]
  #pragma unroll
  for (int t = 0; t < 4; ++t)
    #pragma unroll
    for (int i = 0; i < 4; ++i)
      part[wave][(t * 16 + g * 4 + i) * 17 + l4] = acc[t][i];
  __syncthreads();

  // reduce 8 K-eighths + per-row partition mask -> global rm
  {
    const int row = tid >> 5, jg = tid & 31;       // 16 rows x 32 j-pairs
    const int j0 = jg * 2;
    int4 sb = *(const int4*)(subs + (rowbase + row) * 4);
    unsigned mbits = (1u << sb.x) | (1u << sb.y) | (1u << sb.z) | (1u << sb.w);
    unsigned short v[2];
    #pragma unroll
    for (int jj = 0; jj < 2; ++jj) {
      const int j = j0 + jj;
      float sum = 0.f;
      #pragma unroll
      for (int w = 0; w < 8; ++w) sum += part[w][j * 17 + row];
      v[jj] = ((mbits >> (j >> 3)) & 1u) ? (unsigned short)f2bf_u(sum)
                                         : (unsigned short)0;
    }
    *(unsigned int*)(rm_g + (rowbase + row) * 64 + j0) =
        (unsigned)v[0] | ((unsigned)v[1] << 16);
  }
}

// ===================== K2: out = base + rm @ W^T  [v15 verbatim] ==========
__global__ __launch_bounds__(256, 4)
void k2_apply(const float* __restrict__ base,
              const unsigned short* __restrict__ rm_g,     // [16384][64]
              const unsigned short* __restrict__ Wb_bf,    // [4096][64]
              float* __restrict__ out)
{
  __shared__ __align__(16) unsigned char smem[36864];   // 4 x [32][72] f32
  const int tid  = threadIdx.x;
  const int wave = tid >> 6;
  const int lane = tid & 63;
  const int l4   = lane & 15;
  const int g    = lane >> 4;
  const long rowbase = (long)blockIdx.x * BM2;
  const int off2 = (blockIdx.x * 5) & 15;

  uint4 a2[2][2];     // [row-tile m][k-split s] from global rm (L2-hot, 2MB)
  #pragma unroll
  for (int m = 0; m < 2; ++m)
    #pragma unroll
    for (int s = 0; s < 2; ++s)
      a2[m][s] = *(const uint4*)(rm_g + (rowbase + m * 16 + l4) * 64 +
                                 s * 32 + g * 8);

  float* cbuf = (float*)(smem + wave * 9216);   // [32][72] f32, wave-private
  #pragma unroll 1
  for (int grp = 0; grp < 16; ++grp) {
    const int ga = (grp + off2) & 15;
    const int cbase = wave * 1024 + ga * 64;
    float4 bb[8];
    #pragma unroll
    for (int v2 = 0; v2 < 8; ++v2) {
      const int r = g + v2 * 4;
      bb[v2] = *(const float4*)(base + (rowbase + r) * D_DIM + cbase + l4 * 4);
    }
    f32x4v a[2][4];
    #pragma unroll
    for (int m = 0; m < 2; ++m)
      #pragma unroll
      for (int t = 0; t < 4; ++t) a[m][t] = (f32x4v){0.f, 0.f, 0.f, 0.f};
    #pragma unroll
    for (int t = 0; t < 4; ++t) {
      #pragma unroll
      for (int s = 0; s < 2; ++s) {
        uint4 bfrag = *(const uint4*)(Wb_bf +
            (size_t)(cbase + t * 16 + l4) * R_DIM + s * 32 + g * 8);
        #pragma unroll
        for (int m = 0; m < 2; ++m)
          a[m][t] = __builtin_amdgcn_mfma_f32_16x16x32_bf16(
              __builtin_bit_cast(bf16vec8, a2[m][s]),
              __builtin_bit_cast(bf16vec8, bfrag), a[m][t], 0, 0, 0);
      }
    }
    #pragma unroll
    for (int m = 0; m < 2; ++m)
      #pragma unroll
      for (int t = 0; t < 4; ++t)
        #pragma unroll
        for (int i = 0; i < 4; ++i)
          cbuf[(m * 16 + g * 4 + i) * 72 + t * 16 + l4] = a[m][t][i];
    __syncthreads();
    #pragma unroll
    for (int v2 = 0; v2 < 8; ++v2) {
      const int r = g + v2 * 4;
      f32x4v cv = *(const f32x4v*)(cbuf + r * 72 + l4 * 4);
      float4 o;
      o.x = cv[0] + bb[v2].x;
      o.y = cv[1] + bb[v2].y;
      o.z = cv[2] + bb[v2].z;
      o.w = cv[3] + bb[v2].w;
      *(float4*)(out + (rowbase + r) * D_DIM + cbase + l4 * 4) = o;
    }
    __syncthreads();
  }
}

// ===================== fused fallback (no ws) [v15 verbatim] ==============
__global__ __launch_bounds__(256, 2)
void lrri_fused_nows(const float* __restrict__ base, const float* __restrict__ srcp,
                     const float* __restrict__ W, const int* __restrict__ subs,
                     float* __restrict__ out)
{
  __shared__ __align__(16) unsigned char smem[70144];
  const int tid  = threadIdx.x;
  const int wave = tid >> 6;
  const int lane = tid & 63;
  const int l4   = lane & 15;
  const int g    = lane >> 4;
  const int rh   = wave >> 1;
  const int kh   = wave & 1;
  const long rowbase = (long)blockIdx.x * BM2;
  const long rowg    = rowbase + rh * 16;
  unsigned char* wbuf = smem + wave * 16384;
  const int off1 = (blockIdx.x * 7) & 63;
  const int off2 = (blockIdx.x * 5) & 15;

  f32x4v acc[4];
  #pragma unroll
  for (int t = 0; t < 4; ++t) acc[t] = (f32x4v){0.f, 0.f, 0.f, 0.f};

  #pragma unroll 1
  for (int c = 0; c < 64; ++c) {
    const int ch = (c + off1) & 63;
    unsigned char* buf = wbuf + (c & 1) * 8192;
    const long colf = kh * 2048 + ch * 32;
    #pragma unroll
    for (int q = 0; q < 2; ++q) {
      const int r = q * 8 + (lane >> 3);
      const unsigned b = ((unsigned)((lane & 7) * 16)) ^ ((unsigned)(r & 7) << 4);
      const long goff = (rowg + r) * (long)D_DIM + colf + (b >> 2);
      async_ld16(base + goff, buf + q * 1024);
      async_ld16(srcp + goff, buf + 2048 + q * 1024);
    }
    asm volatile("s_waitcnt vmcnt(0)" ::: "memory");
    __builtin_amdgcn_sched_barrier(0);
    const unsigned sw = (unsigned)((l4 & 7) << 4);
    const unsigned c0 = ((unsigned)(g * 32)) ^ sw;
    const unsigned c1 = ((unsigned)(g * 32 + 16)) ^ sw;
    float4 fb0 = *(const float4*)(buf + l4 * 128 + c0);
    float4 fb1 = *(const float4*)(buf + l4 * 128 + c1);
    float4 fs0 = *(const float4*)(buf + 2048 + l4 * 128 + c0);
    float4 fs1 = *(const float4*)(buf + 2048 + l4 * 128 + c1);
    uint4 af;
    af.x = pack2bf(fs0.x - fb0.x, fs0.y - fb0.y);
    af.y = pack2bf(fs0.z - fb0.z, fs0.w - fb0.w);
    af.z = pack2bf(fs1.x - fb1.x, fs1.y - fb1.y);
    af.w = pack2bf(fs1.z - fb1.z, fs1.w - fb1.w);
    #pragma unroll
    for (int t = 0; t < 4; ++t) {
      unsigned int pq[4];
      #pragma unroll
      for (int e2 = 0; e2 < 4; ++e2) {
        float wa = W[(size_t)(colf + g * 8 + e2 * 2    ) * R_DIM + t * 16 + l4];
        float wb = W[(size_t)(colf + g * 8 + e2 * 2 + 1) * R_DIM + t * 16 + l4];
        pq[e2] = pack2bf(wa, wb);
      }
      uint4 wf; wf.x = pq[0]; wf.y = pq[1]; wf.z = pq[2]; wf.w = pq[3];
      acc[t] = __builtin_amdgcn_mfma_f32_16x16x32_bf16(
          __builtin_bit_cast(bf16vec8, af),
          __builtin_bit_cast(bf16vec8, wf), acc[t], 0, 0, 0);
    }
  }

  {
    float* part = (float*)wbuf;
    #pragma unroll
    for (int t = 0; t < 4; ++t)
      #pragma unroll
      for (int i = 0; i < 4; ++i)
        part[(g * 4 + i) * 72 + t * 16 + l4] = acc[t][i];
  }
  __syncthreads();

  {
    const int row = tid >> 3, jg = tid & 7;
    const int lr  = row & 15;
    const float* pa = (const float*)(smem + ((row >> 4) * 2 + 0) * 16384);
    const float* pb = (const float*)(smem + ((row >> 4) * 2 + 1) * 16384);
    int4 sb = *(const int4*)(subs + (rowbase + row) * 4);
    unsigned mbits = (1u << sb.x) | (1u << sb.y) | (1u << sb.z) | (1u << sb.w);
    unsigned short v[8];
    #pragma unroll
    for (int jj = 0; jj < 8; ++jj) {
      const int j = jg * 8 + jj;
      float sum = pa[lr * 72 + j] + pb[lr * 72 + j];
      v[jj] = ((mbits >> (j >> 3)) & 1u) ? (unsigned short)f2bf_u(sum)
                                         : (unsigned short)0;
    }
    uint4 pk;
    pk.x = (unsigned)v[0] | ((unsigned)v[1] << 16);
    pk.y = (unsigned)v[2] | ((unsigned)v[3] << 16);
    pk.z = (unsigned)v[4] | ((unsigned)v[5] << 16);
    pk.w = (unsigned)v[6] | ((unsigned)v[7] << 16);
    *(uint4*)(smem + 65536 + row * 144 + jg * 16) = pk;
  }
  __syncthreads();

  uint4 a2[2][2];
  #pragma unroll
  for (int m = 0; m < 2; ++m)
    #pragma unroll
    for (int s = 0; s < 2; ++s)
      a2[m][s] = *(const uint4*)(smem + 65536 + (m * 16 + l4) * 144 +
                                 s * 64 + g * 16);
  float* cbuf = (float*)wbuf;
  #pragma unroll 1
  for (int grp = 0; grp < 16; ++grp) {
    const int ga = (grp + off2) & 15;
    const int cbase = wave * 1024 + ga * 64;
    float4 bb[8];
    #pragma unroll
    for (int v2 = 0; v2 < 8; ++v2) {
      const int r = g + v2 * 4;
      bb[v2] = *(const float4*)(base + (rowbase + r) * D_DIM + cbase + l4 * 4);
    }
    f32x4v a[2][4];
    #pragma unroll
    for (int m = 0; m < 2; ++m)
      #pragma unroll
      for (int t = 0; t < 4; ++t) a[m][t] = (f32x4v){0.f, 0.f, 0.f, 0.f};
    #pragma unroll
    for (int t = 0; t < 4; ++t) {
      #pragma unroll
      for (int s = 0; s < 2; ++s) {
        const float* wp = W + (size_t)(cbase + t * 16 + l4) * R_DIM + s * 32 + g * 8;
        float4 wa = *(const float4*)(wp);
        float4 wb2 = *(const float4*)(wp + 4);
        uint4 bfrag;
        bfrag.x = pack2bf(wa.x, wa.y); bfrag.y = pack2bf(wa.z, wa.w);
        bfrag.z = pack2bf(wb2.x, wb2.y); bfrag.w = pack2bf(wb2.z, wb2.w);
        #pragma unroll
        for (int m = 0; m < 2; ++m)
          a[m][t] = __builtin_amdgcn_mfma_f32_16x16x32_bf16(
              __builtin_bit_cast(bf16vec8, a2[m][s]),
              __builtin_bit_cast(bf16vec8, bfrag), a[m][t], 0, 0, 0);
      }
    }
    #pragma unroll
    for (int m = 0; m < 2; ++m)
      #pragma unroll
      for (int t = 0; t < 4; ++t)
        #pragma unroll
        for (int i = 0; i < 4; ++i)
          cbuf[(m * 16 + g * 4 + i) * 72 + t * 16 + l4] = a[m][t][i];
    #pragma unroll
    for (int v2 = 0; v2 < 8; ++v2) {
      const int r = g + v2 * 4;
      f32x4v cv = *(const f32x4v*)(cbuf + r * 72 + l4 * 4);
      float4 o;
      o.x = cv[0] + bb[v2].x;
      o.y = cv[1] + bb[v2].y;
      o.z = cv[2] + bb[v2].z;
      o.w = cv[3] + bb[v2].w;
      *(float4*)(out + (rowbase + r) * D_DIM + cbase + l4 * 4) = o;
    }
  }
}

extern "C" void kernel_launch(void* const* d_in, const int* in_sizes, int n_in,
                              void* d_out, int out_size, void* d_ws, size_t ws_size,
                              hipStream_t stream) {
  const float* base = (const float*)d_in[0];
  const float* srcp = (const float*)d_in[1];
  const float* W    = (const float*)d_in[2];
  const int*   subs = (const int*)d_in[3];
  float* out = (float*)d_out;

  const size_t wconv = (size_t)2 * R_DIM * D_DIM * sizeof(unsigned short); // 1 MB
  const size_t rmsz  = (size_t)16384 * R_DIM * sizeof(unsigned short);     // 2 MB
  if (d_ws && ws_size >= wconv + rmsz) {
    unsigned short* Wt = (unsigned short*)d_ws;          // [64][4096] bf16
    unsigned short* Wb = Wt + (size_t)R_DIM * D_DIM;     // [4096][64] bf16
    unsigned short* rm = Wb + (size_t)R_DIM * D_DIM;     // [16384][64] bf16
    lrri_prep<<<256, 256, 0, stream>>>(W, Wt, Wb);
    k1_rotdiff<<<16384 / BM1, 512, 0, stream>>>(base, srcp, subs, Wt, rm);
    k2_apply<<<16384 / BM2, 256, 0, stream>>>(base, rm, Wb, out);
  } else {
    lrri_fused_nows<<<16384 / BM2, 256, 0, stream>>>(base, srcp, W, subs, out);
  }
}